// Round 5
// baseline (373.290 us; speedup 1.0000x reference)
//
#include <hip/hip_runtime.h>
#include <math.h>

// Problem constants (fixed-shape problem)
#define NN 131072   // nodes
#define G  256      // groups
#define E  384      // embed
#define H  6        // heads
#define DH 64       // head dim
#define OUTD 256    // output dim
#define MAXN 1024   // max segment length

#define CHK 128     // nodes per fused-pool chunk
#define SLOTS 8     // max chunks per group (ceil(MAXN/CHK))
#define PART_STRIDE 2316   // 6*384 acc + 6 m + 6 l

// Workspace layout (float indices)
#define WS_QK   0                       // 6*384 folded q@Wk
#define WS_C    2304                    // 6 folded q@bk
#define WS_OFF  2432                    // 256 int32 segment offsets
#define WS_QV   2944                    // 384 projected+scaled query
#define WS_WL   3328                    // 2048 int32 worklist (g<<3|s)
#define WS_M    5376                    // 1 int32 worklist count
#define WS_PART 5632                    // 2048 slots x 2316 partials
#define WS_WVT  (WS_PART + G*SLOTS*PART_STRIDE)  // 384x384 Wv^T [e][i]
#define WS_WOT  (WS_WVT + E*E)          // 384x384 Wo^T [e][i]
#define WS_WPT  (WS_WOT + E*E)          // 384x256 Wp^T [e][o]

// ---------------------------------------------------------------------------
// K0a: block 0: offset scan + compacted chunk worklist. blocks 1..96: qv rows.
// qv = 0.125*(query@Wq.T + bq)
// ---------------------------------------------------------------------------
__global__ __launch_bounds__(256) void k0a_scan_qv(
    const int* __restrict__ sizes, const float* __restrict__ query,
    const float* __restrict__ Wq, const float* __restrict__ bq,
    float* __restrict__ wsf) {
  const int tid = threadIdx.x;
  if (blockIdx.x == 0) {
    __shared__ int s_scan[G];
    __shared__ int s_scan2[G];
    const int sz = sizes[tid];
    s_scan[tid] = sz;
    const int nch = (sz + CHK - 1) >> 7;           // 1..8
    s_scan2[tid] = nch;
    __syncthreads();
    for (int d = 1; d < G; d <<= 1) {
      int t = (tid >= d) ? s_scan[tid - d] : 0;
      int t2 = (tid >= d) ? s_scan2[tid - d] : 0;
      __syncthreads();
      s_scan[tid] += t;
      s_scan2[tid] += t2;
      __syncthreads();
    }
    int* offs = (int*)(wsf + WS_OFF);
    offs[tid] = s_scan[tid] - sz;                  // exclusive
    int* wl = (int*)(wsf + WS_WL);
    const int pos = s_scan2[tid] - nch;
    for (int s = 0; s < nch; s++) wl[pos + s] = (tid << 3) | s;
    if (tid == G - 1) ((int*)(wsf + WS_M))[0] = s_scan2[G - 1];
  } else {
    const int lane = tid & 63;
    const int i = (blockIdx.x - 1) * 4 + (tid >> 6);   // 0..383
    float a = 0.f;
#pragma unroll
    for (int j = 0; j < 6; j++)
      a += Wq[(size_t)i * E + j * 64 + lane] * query[j * 64 + lane];
#pragma unroll
    for (int mm = 1; mm < 64; mm <<= 1) a += __shfl_xor(a, mm, 64);
    if (lane == 0) wsf[WS_QV + i] = 0.125f * (a + bq[i]);
  }
}

// ---------------------------------------------------------------------------
// K0b: qk[h][e] = sum_d qv[h*64+d]*Wk[h*64+d][e].  36 blocks = (h, e-chunk64).
// ---------------------------------------------------------------------------
__global__ __launch_bounds__(256) void k0b_qk(
    const float* __restrict__ Wk, const float* __restrict__ bk,
    float* __restrict__ wsf) {
  __shared__ float qv_s[64];
  __shared__ float ps[256];
  const int h = blockIdx.x / 6, ec = blockIdx.x % 6;
  const int tid = threadIdx.x;
  if (tid < 64) qv_s[tid] = wsf[WS_QV + h * 64 + tid];
  __syncthreads();
  const int el = tid & 63, dq = tid >> 6;
  float a = 0.f;
#pragma unroll 4
  for (int d = dq * 16; d < dq * 16 + 16; d++)
    a += qv_s[d] * Wk[(size_t)(h * 64 + d) * E + ec * 64 + el];
  ps[tid] = a;
  __syncthreads();
  if (tid < 64)
    wsf[WS_QK + h * E + ec * 64 + tid] =
        ps[tid] + ps[64 + tid] + ps[128 + tid] + ps[192 + tid];
  if (ec == 0 && tid < 64) {                       // wave 0: c[h]
    float p = qv_s[tid] * bk[h * 64 + tid];
#pragma unroll
    for (int mm = 1; mm < 64; mm <<= 1) p += __shfl_xor(p, mm, 64);
    if (tid == 0) wsf[WS_C + h] = p;
  }
}

// ---------------------------------------------------------------------------
// K0t: transpose Wv, Wo (384x384) and Wp (256x384) into ws, 64x64 LDS tiles.
// ---------------------------------------------------------------------------
__global__ __launch_bounds__(256) void k0t_transpose(
    const float* __restrict__ Wv, const float* __restrict__ Wo,
    const float* __restrict__ Wp, float* __restrict__ wsf) {
  __shared__ float s[64][65];
  const int b = blockIdx.x;
  const float* src;
  float* dst;
  int R, tr, tc;
  if (b < 36)      { src = Wv; dst = wsf + WS_WVT; R = 384; tr = b / 6;        tc = b % 6; }
  else if (b < 72) { src = Wo; dst = wsf + WS_WOT; R = 384; tr = (b - 36) / 6; tc = (b - 36) % 6; }
  else             { src = Wp; dst = wsf + WS_WPT; R = 256; tr = (b - 72) / 6; tc = (b - 72) % 6; }
  const int r0 = tr * 64, c0 = tc * 64;
#pragma unroll
  for (int k = 0; k < 16; k++) {
    int idx = k * 256 + threadIdx.x;
    int r = idx >> 6, cc = idx & 63;
    s[r][cc] = src[(size_t)(r0 + r) * E + c0 + cc];
  }
  __syncthreads();
#pragma unroll
  for (int k = 0; k < 16; k++) {
    int idx = k * 256 + threadIdx.x;
    int cc = idx >> 6, r = idx & 63;
    dst[(size_t)(c0 + cc) * R + r0 + r] = s[r][cc];
  }
}

// ---------------------------------------------------------------------------
// K12: fused scores + chunk-local softmax + weighted pooling.  Work item =
// alive chunk of 128 nodes from the compacted worklist (uniform balance).
// 256 thr / 4 waves.  Phase 1: 8-lane scores from HBM -> LDS pbuf.
// Softmax: wave w owns heads {w, w+4} (in-wave, no barriers).
// Phase 2: thread = float4-column (96 f4cols x 2 node-halves; wave 3 idle),
// 64 coalesced float4 re-reads (cache-hot), 24 indep acc chains, one combine.
// ---------------------------------------------------------------------------
#define PB 136      // pbuf stride (floats): 16B-aligned
__global__ __launch_bounds__(256) void k12_fused(
    const float* __restrict__ x, const int* __restrict__ sizes,
    float* __restrict__ wsf) {
  __shared__ float u_mem[4608];        // union: qk_l (2336) | psum (4608)
  __shared__ float pbuf[H * PB];
  __shared__ float c_s[8];
  const int M = ((const int*)(wsf + WS_M))[0];
  if ((int)blockIdx.x >= M) return;
  const int item = ((const int*)(wsf + WS_WL))[blockIdx.x];
  const int g = item >> 3, s = item & 7;
  const int Ng = sizes[g];
  const int rem = Ng - s * CHK;
  const int clen = rem < CHK ? rem : CHK;
  const int n0 = ((const int*)(wsf + WS_OFF))[g] + s * CHK;
  const int tid = threadIdx.x;

  float* qk_l = u_mem;                 // phase-1 layout, k1-proven
  for (int idx = tid; idx < 2304; idx += 256) {
    int sub = idx / 288, r3 = idx % 288;
    int h = r3 / 48, r2 = r3 % 48, j = r2 >> 2, r = r2 & 3;
    qk_l[sub * 292 + h * 48 + j * 4 + r] =
        wsf[WS_QK + h * E + (j * 8 + sub) * 4 + r];
  }
  if (tid < 8) c_s[tid] = (tid < 6) ? wsf[WS_C + tid] : 0.f;
  __syncthreads();

  const int lane = tid & 63, w = tid >> 6;         // 4 waves
  const int sub = lane & 7, nod = lane >> 3;
  const float4* x4 = (const float4*)x;
  {  // phase 1: 32 nodes per wave
    const int base = w * 32;
    float acc[4][6];
#pragma unroll
    for (int o = 0; o < 4; o++)
#pragma unroll
      for (int h = 0; h < 6; h++) acc[o][h] = 0.f;
#pragma unroll 4
    for (int j = 0; j < 12; j++) {
      float4 qk4[6];
#pragma unroll
      for (int h = 0; h < 6; h++)
        qk4[h] = *(const float4*)&qk_l[sub * 292 + h * 48 + j * 4];
      float4 xv[4];
#pragma unroll
      for (int o = 0; o < 4; o++) {
        int nn = base + o * 8 + nod;
        nn = nn < clen ? nn : clen - 1;
        xv[o] = x4[(size_t)(n0 + nn) * 96 + j * 8 + sub];
      }
#pragma unroll
      for (int o = 0; o < 4; o++)
#pragma unroll
        for (int h = 0; h < 6; h++)
          acc[o][h] += qk4[h].x * xv[o].x + qk4[h].y * xv[o].y
                     + qk4[h].z * xv[o].z + qk4[h].w * xv[o].w;
    }
#pragma unroll
    for (int o = 0; o < 4; o++) {
#pragma unroll
      for (int h = 0; h < 6; h++) {
        acc[o][h] += __shfl_xor(acc[o][h], 1, 64);
        acc[o][h] += __shfl_xor(acc[o][h], 2, 64);
        acc[o][h] += __shfl_xor(acc[o][h], 4, 64);
      }
      float v = acc[o][0];
#pragma unroll
      for (int h = 1; h < 6; h++) v = (sub == h) ? acc[o][h] : v;
      if (sub < 6) {
        int nn = base + o * 8 + nod;
        pbuf[sub * PB + nn] = (nn < clen) ? v + c_s[sub] : -1.0e30f;
      }
    }
  }
  __syncthreads();

  float* pslot = wsf + WS_PART + (size_t)blockIdx.x * PART_STRIDE;
  // softmax: wave w -> heads {w, w+4}; all in-wave
  for (int h = w; h < 6; h += 4) {
    float v0 = pbuf[h * PB + lane], v1 = pbuf[h * PB + 64 + lane];
    float m = fmaxf(v0, v1);
#pragma unroll
    for (int mm = 1; mm < 64; mm <<= 1) m = fmaxf(m, __shfl_xor(m, mm, 64));
    float e0 = __expf(v0 - m), e1 = __expf(v1 - m);
    pbuf[h * PB + lane] = e0;
    pbuf[h * PB + 64 + lane] = e1;
    float l = e0 + e1;
#pragma unroll
    for (int mm = 1; mm < 64; mm <<= 1) l += __shfl_xor(l, mm, 64);
    if (lane == 0) { pslot[2304 + h] = m; pslot[2310 + h] = l; }
  }
  __syncthreads();

  // phase 2: thread (f4col 0..95, np 0..1), waves 0-2; wave 3 idle (uniform)
  float* psum = u_mem;                 // [np][h][e] = [2][6][384]
  if (tid < 192) {
    const int f4 = tid % 96, np = tid / 96;
    float acc[6][4];
#pragma unroll
    for (int h = 0; h < 6; h++)
#pragma unroll
      for (int c = 0; c < 4; c++) acc[h][c] = 0.f;
#pragma unroll 2
    for (int n = 0; n < 64; n += 4) {
      float4 xv[4];
#pragma unroll
      for (int k = 0; k < 4; k++) {
        int nn = np * 64 + n + k;
        nn = nn < clen ? nn : clen - 1;            // pad weight is 0
        xv[k] = x4[(size_t)(n0 + nn) * 96 + f4];
      }
#pragma unroll
      for (int h = 0; h < 6; h++) {
        const float4 p = *(const float4*)&pbuf[h * PB + np * 64 + n];
#pragma unroll
        for (int c = 0; c < 4; c++) {
          const float* xc = (const float*)&xv[0];  // not used; keep simple
        }
        acc[h][0] += p.x * xv[0].x + p.y * xv[1].x + p.z * xv[2].x + p.w * xv[3].x;
        acc[h][1] += p.x * xv[0].y + p.y * xv[1].y + p.z * xv[2].y + p.w * xv[3].y;
        acc[h][2] += p.x * xv[0].z + p.y * xv[1].z + p.z * xv[2].z + p.w * xv[3].z;
        acc[h][3] += p.x * xv[0].w + p.y * xv[1].w + p.z * xv[2].w + p.w * xv[3].w;
      }
    }
#pragma unroll
    for (int h = 0; h < 6; h++)
      *(float4*)&psum[(np * 6 + h) * E + f4 * 4] =
          make_float4(acc[h][0], acc[h][1], acc[h][2], acc[h][3]);
  }
  __syncthreads();
  for (int idx = tid; idx < 2304; idx += 256)
    pslot[idx] = psum[idx] + psum[2304 + idx];
}

// ---------------------------------------------------------------------------
// K3: one block (768 thr) per group.  Prologue: flash-combine <=8 chunk
// partials (indexed via worklist positions = chunk-scan) -> xb.  Then
// thread-per-output chain on transposed weights (coalesced, L2-resident).
// ---------------------------------------------------------------------------
__global__ __launch_bounds__(768) void k3_group(
    const float* __restrict__ wsf, const int* __restrict__ sizes,
    const float* __restrict__ bv, const float* __restrict__ bo,
    const float* __restrict__ bp, float* __restrict__ out) {
  __shared__ float xb[H * E];          // 9.2 KB
  __shared__ float pooled[E];
  __shared__ float om[E];
  __shared__ float ps[768];
  __shared__ float wgt[SLOTS][H];
  __shared__ float linv[H];
  __shared__ int base_s;
  const int tid = threadIdx.x;
  const int g = blockIdx.x;
  const int nch = (sizes[g] + CHK - 1) >> 7;       // 1..8
  if (tid == 0) {
    // worklist position of (g,0): count chunks of groups < g
    int b = 0;
    for (int gg = 0; gg < g; gg++) b += (sizes[gg] + CHK - 1) >> 7;
    base_s = b;
  }
  __syncthreads();
  const float* pg = wsf + WS_PART + (size_t)base_s * PART_STRIDE;
  const float* wvt = wsf + WS_WVT;
  const float* wot = wsf + WS_WOT;
  const float* wpt = wsf + WS_WPT;

  if (tid < H) {
    float m = -3.0e38f;
    for (int s = 0; s < nch; s++)
      m = fmaxf(m, pg[(size_t)s * PART_STRIDE + 2304 + tid]);
    float L = 0.f;
    for (int s = 0; s < nch; s++) {
      float wv_ = __expf(pg[(size_t)s * PART_STRIDE + 2304 + tid] - m);
      wgt[s][tid] = wv_;
      L += pg[(size_t)s * PART_STRIDE + 2310 + tid] * wv_;
    }
    linv[tid] = 1.f / L;
  }
  __syncthreads();
  for (int idx = tid; idx < H * E; idx += 768) {
    int h = idx / E;
    float a = 0.f;
    for (int s = 0; s < nch; s++) a += pg[(size_t)s * PART_STRIDE + idx] * wgt[s][h];
    xb[idx] = a * linv[h];
  }
  __syncthreads();

  {  // stage 1: pooled[i] = Wv[i,:]·xb[head(i),:] + bv
    const int i = tid % 384, ks = tid / 384;
    const float* xh = xb + (i >> 6) * E + ks * 192;
    const float* wp_ = wvt + (size_t)(ks * 192) * E + i;
    float a0 = 0.f, a1 = 0.f, a2 = 0.f, a3 = 0.f;
#pragma unroll 4
    for (int e = 0; e < 192; e += 4) {
      a0 += wp_[(size_t)(e + 0) * E] * xh[e + 0];
      a1 += wp_[(size_t)(e + 1) * E] * xh[e + 1];
      a2 += wp_[(size_t)(e + 2) * E] * xh[e + 2];
      a3 += wp_[(size_t)(e + 3) * E] * xh[e + 3];
    }
    ps[tid] = (a0 + a1) + (a2 + a3);
  }
  __syncthreads();
  if (tid < 384) pooled[tid] = ps[tid] + ps[384 + tid] + bv[tid];
  __syncthreads();

  {  // stage 2: om[i] = Wo[i,:]·pooled + bo
    const int i = tid % 384, ks = tid / 384;
    const float* xh = pooled + ks * 192;
    const float* wp_ = wot + (size_t)(ks * 192) * E + i;
    float a0 = 0.f, a1 = 0.f, a2 = 0.f, a3 = 0.f;
#pragma unroll 4
    for (int e = 0; e < 192; e += 4) {
      a0 += wp_[(size_t)(e + 0) * E] * xh[e + 0];
      a1 += wp_[(size_t)(e + 1) * E] * xh[e + 1];
      a2 += wp_[(size_t)(e + 2) * E] * xh[e + 2];
      a3 += wp_[(size_t)(e + 3) * E] * xh[e + 3];
    }
    ps[tid] = (a0 + a1) + (a2 + a3);
  }
  __syncthreads();
  if (tid < 384) om[tid] = ps[tid] + ps[384 + tid] + bo[tid];
  __syncthreads();

  {  // stage 3: out[o] = Wp[o,:]·om + bp   (3-way K-split of 384)
    const int o = tid % 256, ks = tid / 256;
    const float* xh = om + ks * 128;
    const float* wp_ = wpt + (size_t)(ks * 128) * OUTD + o;
    float a0 = 0.f, a1 = 0.f, a2 = 0.f, a3 = 0.f;
#pragma unroll 4
    for (int e = 0; e < 128; e += 4) {
      a0 += wp_[(size_t)(e + 0) * OUTD] * xh[e + 0];
      a1 += wp_[(size_t)(e + 1) * OUTD] * xh[e + 1];
      a2 += wp_[(size_t)(e + 2) * OUTD] * xh[e + 2];
      a3 += wp_[(size_t)(e + 3) * OUTD] * xh[e + 3];
    }
    ps[tid] = (a0 + a1) + (a2 + a3);
  }
  __syncthreads();
  if (tid < 256)
    out[(size_t)g * OUTD + tid] = ps[tid] + ps[256 + tid] + ps[512 + tid] + bp[tid];
}

// ---------------------------------------------------------------------------
extern "C" void kernel_launch(void* const* d_in, const int* in_sizes, int n_in,
                              void* d_out, int out_size, void* d_ws, size_t ws_size,
                              hipStream_t stream) {
  const float* x     = (const float*)d_in[0];
  const int*   sizes = (const int*)d_in[1];
  const float* query = (const float*)d_in[2];
  const float* Wq    = (const float*)d_in[3];
  const float* bq    = (const float*)d_in[4];
  const float* Wk    = (const float*)d_in[5];
  const float* bk    = (const float*)d_in[6];
  const float* Wv    = (const float*)d_in[7];
  const float* bv    = (const float*)d_in[8];
  const float* Wo    = (const float*)d_in[9];
  const float* bo    = (const float*)d_in[10];
  const float* Wp    = (const float*)d_in[11];
  const float* bp    = (const float*)d_in[12];
  float* wsf = (float*)d_ws;
  float* out = (float*)d_out;

  hipLaunchKernelGGL(k0a_scan_qv, dim3(97), dim3(256), 0, stream,
                     sizes, query, Wq, bq, wsf);
  hipLaunchKernelGGL(k0b_qk, dim3(36), dim3(256), 0, stream, Wk, bk, wsf);
  hipLaunchKernelGGL(k0t_transpose, dim3(96), dim3(256), 0, stream,
                     Wv, Wo, Wp, wsf);
  hipLaunchKernelGGL(k12_fused, dim3(G * SLOTS), dim3(256), 0, stream,
                     x, sizes, wsf);
  hipLaunchKernelGGL(k3_group, dim3(G), dim3(768), 0, stream,
                     wsf, sizes, bv, bo, bp, out);
}